// Round 7
// baseline (18436.121 us; speedup 1.0000x reference)
//
#include <hip/hip_runtime.h>
#include <cmath>

typedef __attribute__((ext_vector_type(8))) short short8;
typedef __attribute__((ext_vector_type(4))) float f32x4;
typedef __attribute__((ext_vector_type(2))) unsigned int uint2v;

#define B_SZ 512
#define T_SZ 256
#define I_SZ 256
#define H_SZ 1024
#define V_SZ 1024
#define E_SZ 8
#define FUT 64

// R5 numerics (3-product split-bf16), new geometry + pipeline.
// Virtual (expanded) K of each packed W; physical (deduped) A strides.
// enc A phys: [x_hi 256 | x_lo 256 | h_hi 1024 | h_lo 1024]          = 2560
// dec A phys: [xc 128 (hi8|hi8|lo8|0) | h_hi 1024 | h_lo 1024]       = 2176
// W_enc virt: [Wih_hi|Wih_lo|Wih_hi | Whh_hi|Whh_lo|Whh_hi]          = 3840
// W_dec virt: [Wxc 128 | Whh_hi|Whh_lo|Whh_hi | 0-pad 128]           = 3328
// W_fc  virt: [Wfc_hi | Wfc_lo | Wfc_hi]                             = 3072
#define KVE 3840
#define KVD 3328
#define KVF 3072
#define APE 2560
#define APD 2176

static __device__ __forceinline__ ushort f2bf(float v) {
    uint32_t u = __float_as_uint(v);
    uint32_t r = (u + 0x7fffu + ((u >> 16) & 1u)) >> 16;
    return (ushort)r;
}
static __device__ __forceinline__ float bf2f(ushort b) {
    return __uint_as_float(((uint32_t)b) << 16);
}

#define GLD16(gp, lp)                                                          \
    __builtin_amdgcn_global_load_lds(                                         \
        (const __attribute__((address_space(1))) void*)(gp),                  \
        (__attribute__((address_space(3))) void*)(lp), 16, 0, 0)

// ---------------------------------------------------------------------------
// Split-bf16 GEMM step, wave-tile 32 x (WNF*16), block 64 x (2*WNF*16),
// 4 waves (2m x 2n). k-tile = 64 virtual cols. Both operands LDS-staged via
// global_load_lds into 3 rotating buffers; counted-vmcnt pipeline (2 k-tiles
// in flight across raw s_barriers, never drained to 0 in steady state).
// LDS rows are 64 bf16 = 128B = 8 16B-slots, XOR-swizzled slot^(row&7):
// global source column pre-swizzled, ds_read applies the same XOR.
// A's virtual K deduped by piecewise source offset (64-aligned boundaries).
//   GATES=true : LSTM epilogue (z-tile LDS exchange, gates, c update,
//                h hi/lo stores, optional x_{t+1} conversion).
//   GATES=false: out = acc + bias.
// ---------------------------------------------------------------------------
template<int WNF, int NTPX, int NK, int T1, int T2, int O0, int O1, int O2,
         bool GATES>
__global__ __launch_bounds__(256) void gemm_step(
    const ushort* __restrict__ A, int astr,
    const ushort* __restrict__ W, int kv,
    const float* __restrict__ bias,
    float* __restrict__ c,
    ushort* __restrict__ hdest, int ldh,
    const float* __restrict__ xsrc, ushort* __restrict__ xdest,
    float* __restrict__ out, int ldo)
{
    constexpr int NRW = 2 * WNF * 16;          // W tile rows (128 or 64)
    __shared__ __align__(16) ushort As[3][64 * 64];    // 24 KB
    __shared__ __align__(16) ushort Ws[3][NRW * 64];   // 48 or 24 KB

    const int tid = threadIdx.x;
    const int lane = tid & 63;
    const int wid = tid >> 6;
    const int wm = wid >> 1, wn = wid & 1;
    const int l15 = lane & 15, lq = lane >> 4;

    const int flat = blockIdx.x;
    const int xcd = flat & 7, slot = flat >> 3;
    const int n_tile = xcd * NTPX + (slot % NTPX);
    const int m_tile = slot / NTPX;
    const int m0 = m_tile * 64;
    const int n0 = n_tile * (2 * WNF * 16);

    f32x4 acc[2][WNF];
#pragma unroll
    for (int m = 0; m < 2; ++m)
#pragma unroll
        for (int n = 0; n < WNF; ++n) { f32x4 z = {0.f, 0.f, 0.f, 0.f}; acc[m][n] = z; }

    const int l7 = lane & 7, l3 = lane >> 3;   // staging row-in-group / slot

    auto STAGE = [&](int p, int bufi) {
        const int off = p < T1 ? O0 : (p < T2 ? O1 : O2);
        const int kc = p * 64;
        // W tile: NRW rows x 64 cols; each wave-iter stages 8 rows x 8 slots.
#pragma unroll
        for (int i = 0; i < NRW / 32; ++i) {
            const int rowg = (i * 4 + wid) * 8;
            const int row = rowg + l3;
            GLD16(W + (size_t)(n0 + row) * kv + kc + ((l7 ^ (row & 7)) * 8),
                  &Ws[bufi][rowg * 64]);
        }
        // A tile: 64 rows x 64 cols.
#pragma unroll
        for (int i = 0; i < 2; ++i) {
            const int rowg = (i * 4 + wid) * 8;
            const int row = rowg + l3;
            GLD16(A + (size_t)(m0 + row) * astr + kc + off + ((l7 ^ (row & 7)) * 8),
                  &As[bufi][rowg * 64]);
        }
    };
    auto COMPUTE = [&](int bufi) {
#pragma unroll
        for (int kk = 0; kk < 2; ++kk) {
            short8 af[2], wf[WNF];
#pragma unroll
            for (int m = 0; m < 2; ++m) {
                const int row = wm * 32 + m * 16 + l15;
                af[m] = *(const short8*)
                    &As[bufi][row * 64 + (((kk * 4 + lq) ^ (row & 7)) * 8)];
            }
#pragma unroll
            for (int n = 0; n < WNF; ++n) {
                const int row = wn * (WNF * 16) + n * 16 + l15;
                wf[n] = *(const short8*)
                    &Ws[bufi][row * 64 + (((kk * 4 + lq) ^ (row & 7)) * 8)];
            }
#pragma unroll
            for (int m = 0; m < 2; ++m)
#pragma unroll
                for (int n = 0; n < WNF; ++n)
                    acc[m][n] = __builtin_amdgcn_mfma_f32_16x16x32_bf16(
                        af[m], wf[n], acc[m][n], 0, 0, 0);
        }
    };

    // ---- pipelined k-loop: wait(counted) -> barrier -> stage -> compute ----
    STAGE(0, 0);
    STAGE(1, 1);
    int bc = 0, bs = 2;
#pragma unroll 1
    for (int kt = 0; kt < NK - 1; ++kt) {
        if constexpr (WNF == 4) asm volatile("s_waitcnt vmcnt(6)" ::: "memory");
        else                    asm volatile("s_waitcnt vmcnt(4)" ::: "memory");
        __builtin_amdgcn_s_barrier();
        __builtin_amdgcn_sched_barrier(0);
        if (kt + 2 < NK) STAGE(kt + 2, bs);
        COMPUTE(bc);
        bc = bc == 2 ? 0 : bc + 1;
        bs = bs == 2 ? 0 : bs + 1;
    }
    asm volatile("s_waitcnt vmcnt(0)" ::: "memory");
    __builtin_amdgcn_s_barrier();
    __builtin_amdgcn_sched_barrier(0);
    COMPUTE(bc);

    // --- epilogue ----------------------------------------------------------
    if constexpr (GATES) {
        float* zs = (float*)&Ws[0][0];        // 64*129*4 = 33 KB <= 48 KB
        __syncthreads();
#pragma unroll
        for (int m = 0; m < 2; ++m)
#pragma unroll
            for (int n = 0; n < WNF; ++n)
#pragma unroll
                for (int r = 0; r < 4; ++r)
                    zs[(wm * 32 + m * 16 + lq * 4 + r) * 129 +
                       wn * (WNF * 16) + n * 16 + l15] = acc[m][n][r];
        __syncthreads();

        const int row = tid & 63;
        const int jb = (tid >> 6) * 8;         // 8 h-cols per thread
        const int grow = m0 + row;
        const int jg = n_tile * 32 + jb;
        f32x4 cv0 = *(f32x4*)&c[(size_t)grow * H_SZ + jg];
        f32x4 cv1 = *(f32x4*)&c[(size_t)grow * H_SZ + jg + 4];
        ushort hh[8], hl[8];
#pragma unroll
        for (int jj = 0; jj < 8; ++jj) {
            const int jl = jb + jj;            // 0..31
            const int nb = (jl >> 4) * 64 + (jl & 15);
            const float zi = zs[row * 129 + nb]      + bias[n0 + nb];
            const float zf = zs[row * 129 + nb + 16] + bias[n0 + nb + 16];
            const float zg = zs[row * 129 + nb + 32] + bias[n0 + nb + 32];
            const float zo = zs[row * 129 + nb + 48] + bias[n0 + nb + 48];
            const float ig = 1.f / (1.f + expf(-zi));
            const float fg = 1.f / (1.f + expf(-zf));
            const float gg = tanhf(zg);
            const float og = 1.f / (1.f + expf(-zo));
            float cvv = jj < 4 ? cv0[jj] : cv1[jj - 4];
            const float cn = fg * cvv + ig * gg;
            if (jj < 4) cv0[jj] = cn; else cv1[jj - 4] = cn;
            const float hv = og * tanhf(cn);
            hh[jj] = f2bf(hv);
            hl[jj] = f2bf(hv - bf2f(hh[jj]));
        }
        *(f32x4*)&c[(size_t)grow * H_SZ + jg] = cv0;
        *(f32x4*)&c[(size_t)grow * H_SZ + jg + 4] = cv1;
        ushort* hd = hdest + (size_t)grow * ldh + jg;
        short8 hv8, lv8;
#pragma unroll
        for (int jj = 0; jj < 8; ++jj) { hv8[jj] = (short)hh[jj]; lv8[jj] = (short)hl[jj]; }
        *(short8*)hd = hv8;
        *(short8*)(hd + 1024) = lv8;           // h_lo always hi_base + 1024

        if (xdest) {                            // fused x_{t+1} conversion
#pragma unroll
            for (int e = 0; e < 2; ++e) {
                const int idx = (flat * 256 + tid) * 2 + e;  // B*I = 131072
                const int b = idx >> 8, i = idx & 255;
                const float v = xsrc[(size_t)b * (T_SZ * I_SZ) + i];
                const ushort hi = f2bf(v), lo = f2bf(v - bf2f(hi));
                xdest[(size_t)b * APE + i] = hi;
                xdest[(size_t)b * APE + 256 + i] = lo;
            }
        }
    } else {
#pragma unroll
        for (int m = 0; m < 2; ++m)
#pragma unroll
            for (int n = 0; n < WNF; ++n) {
                const int col = n0 + wn * (WNF * 16) + n * 16 + l15;
                const float bv = bias[col];
#pragma unroll
                for (int r = 0; r < 4; ++r) {
                    const int row = m0 + wm * 32 + m * 16 + lq * 4 + r;
                    out[(size_t)row * ldo + col] = acc[m][n][r] + bv;
                }
            }
    }
}

// ---------------------------------------------------------------------------
// Row argmax (first-occurrence) + embedding gather into next dec A's xc.
// ---------------------------------------------------------------------------
__global__ __launch_bounds__(256) void argmax_embed(
    const float* __restrict__ logits, int ldl,
    const float* __restrict__ embed_W,
    ushort* __restrict__ xdest)
{
    const int b = blockIdx.x;
    const float* row = logits + (size_t)b * ldl;
    const int tid = threadIdx.x;
    float best = -INFINITY;
    int bi = V_SZ;
#pragma unroll
    for (int v = tid; v < V_SZ; v += 256) {
        const float x = row[v];
        if (x > best) { best = x; bi = v; }
    }
    __shared__ float sv[256];
    __shared__ int si[256];
    sv[tid] = best; si[tid] = bi;
    __syncthreads();
    for (int s = 128; s > 0; s >>= 1) {
        if (tid < s) {
            const float ov = sv[tid + s]; const int oi = si[tid + s];
            if (ov > sv[tid] || (ov == sv[tid] && oi < si[tid])) { sv[tid] = ov; si[tid] = oi; }
        }
        __syncthreads();
    }
    if (tid < E_SZ) {
        const int yb = si[0];
        const float v = embed_W[(size_t)yb * E_SZ + tid];
        const ushort hi = f2bf(v), lo = f2bf(v - bf2f(hi));
        ushort* xd = xdest + (size_t)b * APD;
        xd[tid] = hi;
        xd[8 + tid] = hi;
        xd[16 + tid] = lo;
    }
}

// ---------------------------------------------------------------------------
// Weight packing (gate-permuted rows n' = jhi*64 + g*16 + jlo). R5 layouts.
// ---------------------------------------------------------------------------
__global__ void pack_enc(const float* __restrict__ Wih, const float* __restrict__ Whh,
                         const float* __restrict__ b, ushort* __restrict__ Wp,
                         float* __restrict__ bp)
{
    const int k = blockIdx.x * 256 + threadIdx.x;   // < 3840
    const int np = blockIdx.y;                      // < 4096
    const int orig = ((np >> 4) & 3) * H_SZ + (np >> 6) * 16 + (np & 15);
    float v; bool lo = false;
    if (k < 256)        v = Wih[(size_t)orig * I_SZ + k];
    else if (k < 512) { v = Wih[(size_t)orig * I_SZ + k - 256]; lo = true; }
    else if (k < 768)   v = Wih[(size_t)orig * I_SZ + k - 512];
    else if (k < 1792)  v = Whh[(size_t)orig * H_SZ + k - 768];
    else if (k < 2816) { v = Whh[(size_t)orig * H_SZ + k - 1792]; lo = true; }
    else                v = Whh[(size_t)orig * H_SZ + k - 2816];
    const ushort hi = f2bf(v);
    Wp[(size_t)np * KVE + k] = lo ? f2bf(v - bf2f(hi)) : hi;
    if (k == 0) bp[np] = b[orig];
}

__global__ void pack_dec(const float* __restrict__ Wih, const float* __restrict__ Whh,
                         const float* __restrict__ b, ushort* __restrict__ Wp,
                         float* __restrict__ bp)
{
    const int k = blockIdx.x * 256 + threadIdx.x;   // < 3328 (13*256 exact)
    const int np = blockIdx.y;
    const int orig = ((np >> 4) & 3) * H_SZ + (np >> 6) * 16 + (np & 15);
    float v = 0.f; bool lo = false; bool zero = false;
    if (k < 8)            v = Wih[(size_t)orig * E_SZ + k];
    else if (k < 16)    { v = Wih[(size_t)orig * E_SZ + k - 8]; lo = true; }
    else if (k < 24)      v = Wih[(size_t)orig * E_SZ + k - 16];
    else if (k < 128)     zero = true;
    else if (k < 1152)    v = Whh[(size_t)orig * H_SZ + k - 128];
    else if (k < 2176)  { v = Whh[(size_t)orig * H_SZ + k - 1152]; lo = true; }
    else if (k < 3200)    v = Whh[(size_t)orig * H_SZ + k - 2176];
    else                  zero = true;
    ushort w = 0;
    if (!zero) { const ushort hi = f2bf(v); w = lo ? f2bf(v - bf2f(hi)) : hi; }
    Wp[(size_t)np * KVD + k] = w;
    if (k == 0) bp[np] = b[orig];
}

__global__ void pack_fc(const float* __restrict__ W, ushort* __restrict__ Wp)
{
    const int k = blockIdx.x * 256 + threadIdx.x;   // < 3072
    const int np = blockIdx.y;                      // < 1024 (no permute)
    float v; bool lo = false;
    if (k < 1024)       v = W[(size_t)np * H_SZ + k];
    else if (k < 2048) { v = W[(size_t)np * H_SZ + k - 1024]; lo = true; }
    else                v = W[(size_t)np * H_SZ + k - 2048];
    const ushort hi = f2bf(v);
    Wp[(size_t)np * KVF + k] = lo ? f2bf(v - bf2f(hi)) : hi;
}

// ---------------------------------------------------------------------------
// Init: zero c + A_enc0 h region; convert x(0); xc(0) from embed row 0;
// zero dec xc pads (both buffers).
// ---------------------------------------------------------------------------
__global__ void init_all(const float* __restrict__ x0,
                         const float* __restrict__ embed_W,
                         float* __restrict__ c,
                         ushort* __restrict__ Aenc0,
                         ushort* __restrict__ Adec0,
                         ushort* __restrict__ Adec1)
{
    const int idx = blockIdx.x * 256 + threadIdx.x;   // < 512*2048
    {
        const int b = idx >> 11, k = idx & 2047;
        Aenc0[(size_t)b * APE + 512 + k] = 0;
    }
    if (idx < B_SZ * H_SZ) c[idx] = 0.f;
    if (idx < B_SZ * I_SZ) {
        const int b = idx >> 8, i = idx & 255;
        const float v = x0[(size_t)b * (T_SZ * I_SZ) + i];
        const ushort hi = f2bf(v), lo = f2bf(v - bf2f(hi));
        Aenc0[(size_t)b * APE + i] = hi;
        Aenc0[(size_t)b * APE + 256 + i] = lo;
    }
    if (idx < B_SZ * 104) {
        const int b = idx / 104, col = 24 + idx % 104;
        Adec0[(size_t)b * APD + col] = 0;
        Adec1[(size_t)b * APD + col] = 0;
    }
    if (idx < B_SZ * 24) {
        const int b = idx / 24, col = idx % 24;
        float v;
        if (col < 8)       v = embed_W[col];
        else if (col < 16) v = embed_W[col - 8];
        else               v = embed_W[col - 16];
        const ushort hi = f2bf(v);
        Adec0[(size_t)b * APD + col] = (col < 16) ? hi : f2bf(v - bf2f(hi));
    }
}

extern "C" void kernel_launch(void* const* d_in, const int* in_sizes, int n_in,
                              void* d_out, int out_size, void* d_ws, size_t ws_size,
                              hipStream_t stream)
{
    const float* x_hist  = (const float*)d_in[0];
    const float* enc_Wih = (const float*)d_in[1];
    const float* enc_Whh = (const float*)d_in[2];
    const float* enc_b   = (const float*)d_in[3];
    const float* embed_W = (const float*)d_in[4];
    const float* dec_Wih = (const float*)d_in[5];
    const float* dec_Whh = (const float*)d_in[6];
    const float* dec_b   = (const float*)d_in[7];
    const float* fc_W    = (const float*)d_in[8];
    const float* fc_b    = (const float*)d_in[9];
    float* out = (float*)d_out;

    char* p = (char*)d_ws;
    auto alloc = [&](size_t bytes) {
        char* r = p;
        p += (bytes + 255) & ~(size_t)255;
        return r;
    };
    ushort* W_enc  = (ushort*)alloc((size_t)4096 * KVE * 2);   // 30 MB
    ushort* W_dec  = (ushort*)alloc((size_t)4096 * KVD * 2);   // 26 MB
    ushort* W_fc   = (ushort*)alloc((size_t)1024 * KVF * 2);   // 6 MB
    ushort* A_enc0 = (ushort*)alloc((size_t)B_SZ * APE * 2);   // 2.5 MB
    ushort* A_enc1 = (ushort*)alloc((size_t)B_SZ * APE * 2);
    ushort* A_dec0 = (ushort*)alloc((size_t)B_SZ * APD * 2);   // 2.13 MB
    ushort* A_dec1 = (ushort*)alloc((size_t)B_SZ * APD * 2);
    float*  cbuf   = (float*)alloc((size_t)B_SZ * H_SZ * 4);   // 2 MB
    float*  bpe    = (float*)alloc(4096 * 4);
    float*  bpd    = (float*)alloc(4096 * 4);

    const dim3 blk(256);
    hipLaunchKernelGGL(pack_enc, dim3(15, 4096), blk, 0, stream, enc_Wih, enc_Whh, enc_b, W_enc, bpe);
    hipLaunchKernelGGL(pack_dec, dim3(13, 4096), blk, 0, stream, dec_Wih, dec_Whh, dec_b, W_dec, bpd);
    hipLaunchKernelGGL(pack_fc,  dim3(12, 1024), blk, 0, stream, fc_W, W_fc);
    hipLaunchKernelGGL(init_all, dim3(4096), blk, 0, stream, x_hist, embed_W, cbuf, A_enc0, A_dec0, A_dec1);

    ushort* Ae[2] = {A_enc0, A_enc1};
    ushort* Ad[2] = {A_dec0, A_dec1};

    // Encoder: A-map offsets per k-tile(64): [0,4):0 [4,28):-256 [28,60):-1280
    for (int t = 0; t < T_SZ; ++t) {
        ushort* hdst; int ldh; const float* xs; ushort* xd;
        if (t < T_SZ - 1) {
            hdst = Ae[(t + 1) & 1] + 512; ldh = APE;
            xs = x_hist + (size_t)(t + 1) * I_SZ;
            xd = Ae[(t + 1) & 1];
        } else {
            hdst = Ad[0] + 128; ldh = APD;
            xs = nullptr; xd = nullptr;
        }
        hipLaunchKernelGGL((gemm_step<4, 4, 60, 4, 28, 0, -256, -1280, true>),
                           dim3(256), blk, 0, stream,
                           Ae[t & 1], APE, W_enc, KVE, bpe, cbuf,
                           hdst, ldh, xs, xd, (float*)nullptr, 0);
    }

    // Decoder: dec map: [0,18):0 [18,50):-1024 [50,52):-3200 (zero-pad tiles)
    // fc map:  [0,16):+128 [16,48):-896
    for (int t = 0; t < FUT; ++t) {
        hipLaunchKernelGGL((gemm_step<4, 4, 52, 18, 50, 0, -1024, -3200, true>),
                           dim3(256), blk, 0, stream,
                           Ad[t & 1], APD, W_dec, KVD, bpd, cbuf,
                           Ad[(t + 1) & 1] + 128, APD,
                           (const float*)nullptr, (ushort*)nullptr,
                           (float*)nullptr, 0);
        float* logits = out + (size_t)t * V_SZ;   // [B, FUT, V]
        hipLaunchKernelGGL((gemm_step<2, 2, 48, 16, 48, 128, -896, -896, false>),
                           dim3(128), blk, 0, stream,
                           Ad[(t + 1) & 1], APD, W_fc, KVF, fc_b,
                           (float*)nullptr, (ushort*)nullptr, 0,
                           (const float*)nullptr, (ushort*)nullptr,
                           logits, FUT * V_SZ);
        hipLaunchKernelGGL(argmax_embed, dim3(512), blk, 0, stream,
                           logits, FUT * V_SZ, embed_W, Ad[(t + 1) & 1]);
    }
}

// Round 8
// 10413.204 us; speedup vs baseline: 1.7705x; 1.7705x over previous
//
#include <hip/hip_runtime.h>
#include <cmath>

typedef __attribute__((ext_vector_type(8))) short short8;
typedef __attribute__((ext_vector_type(4))) float f32x4;

#define B_SZ 512
#define T_SZ 256
#define I_SZ 256
#define H_SZ 1024
#define V_SZ 1024
#define E_SZ 8
#define FUT 64

// R5 numerics (3-product split-bf16). Physical A / virtual W layouts:
// enc A phys: [x_hi 256 | x_lo 256 | h_hi 1024 | h_lo 1024]          = 2560
// dec A phys: [xc 128 (hi8|hi8|lo8|0) | h_hi 1024 | h_lo 1024]       = 2176
// W_enc virt: [Wih_hi|Wih_lo|Wih_hi | Whh_hi|Whh_lo|Whh_hi]          = 3840
// W_dec virt: [Wxc 128 | Whh_hi|Whh_lo|Whh_hi | 0-pad 128]           = 3328
// W_fc  virt: [Wfc_hi | Wfc_lo | Wfc_hi]                             = 3072
#define KVE 3840
#define KVD 3328
#define KVF 3072
#define APE 2560
#define APD 2176

static __device__ __forceinline__ ushort f2bf(float v) {
    uint32_t u = __float_as_uint(v);
    uint32_t r = (u + 0x7fffu + ((u >> 16) & 1u)) >> 16;
    return (ushort)r;
}
static __device__ __forceinline__ float bf2f(ushort b) {
    return __uint_as_float(((uint32_t)b) << 16);
}

#define GLD16(gp, lp)                                                          \
    __builtin_amdgcn_global_load_lds(                                         \
        (const __attribute__((address_space(1))) void*)(gp),                  \
        (__attribute__((address_space(3))) void*)(lp), 16, 0, 0)

// ---------------------------------------------------------------------------
// Split-bf16 GEMM step. Block tile 64x64, 4 waves (2m x 2n), wave tile 32x32.
// BK=64. Both operands staged via global_load_lds into 4 rotating buffers
// (64 KB total -> 2 blocks/CU, 8 waves/CU). Counted-vmcnt pipeline: stage
// k-tile p+3 while computing p; steady-state wait = vmcnt(8) (stage p done,
// 2 stages in flight) -- no vmcnt(0) drain inside the loop.
// LDS rows: 64 bf16 = 128B = 8 16B-slots, XOR-swizzled slot^(row&7); global
// source column pre-swizzled, ds_read applies the same XOR (T2, rule #21).
// A's virtual K deduped by piecewise source offset (64-aligned boundaries).
// ---------------------------------------------------------------------------
template<int NTPX, int NK, int T1, int T2, int O0, int O1, int O2, bool GATES>
__global__ __launch_bounds__(256) void gemm_step(
    const ushort* __restrict__ A, int astr,
    const ushort* __restrict__ W, int kv,
    const float* __restrict__ bias,
    float* __restrict__ c,
    ushort* __restrict__ hdest, int ldh,
    const float* __restrict__ xsrc, ushort* __restrict__ xdest,
    float* __restrict__ out, int ldo)
{
    // [0,16384): A bufs 0..3 (4 x 8 KB); [16384,32768): W bufs 0..3.
    __shared__ __align__(16) ushort lds[32768];   // 64 KB

    const int tid = threadIdx.x;
    const int lane = tid & 63;
    const int wid = tid >> 6;
    const int wm = wid >> 1, wn = wid & 1;
    const int l15 = lane & 15, lq = lane >> 4;
    const int l7 = lane & 7, l3 = lane >> 3;

    const int flat = blockIdx.x;
    const int xcd = flat & 7, slot = flat >> 3;
    const int n_tile = xcd * NTPX + (slot % NTPX);
    const int m_tile = slot / NTPX;
    const int m0 = m_tile * 64;
    const int n0 = n_tile * 64;

    f32x4 acc[2][2];
#pragma unroll
    for (int m = 0; m < 2; ++m)
#pragma unroll
        for (int n = 0; n < 2; ++n) { f32x4 z = {0.f, 0.f, 0.f, 0.f}; acc[m][n] = z; }

    // Stage k-tile p (64 cols of A and W) into buffer bufi. 4 GLD16/wave.
    auto STAGE = [&](int p, int bufi) {
        const int off = p < T1 ? O0 : (p < T2 ? O1 : O2);
        const int kc = p * 64;
        ushort* ab = &lds[bufi * 4096];
        ushort* wb = &lds[16384 + bufi * 4096];
#pragma unroll
        for (int i = 0; i < 2; ++i) {
            const int rowg = (i * 4 + wid) * 8;    // 8-row group base
            const int row = rowg + l3;
            GLD16(W + (size_t)(n0 + row) * kv + kc + ((l7 ^ l3) * 8),
                  wb + rowg * 64);
            GLD16(A + (size_t)(m0 + row) * astr + kc + off + ((l7 ^ l3) * 8),
                  ab + rowg * 64);
        }
    };
    auto COMPUTE = [&](int bufi) {
        const ushort* ab = &lds[bufi * 4096];
        const ushort* wb = &lds[16384 + bufi * 4096];
#pragma unroll
        for (int kk = 0; kk < 2; ++kk) {
            short8 af[2], wf[2];
#pragma unroll
            for (int m = 0; m < 2; ++m) {
                const int row = wm * 32 + m * 16 + l15;
                af[m] = *(const short8*)
                    &ab[row * 64 + (((kk * 4 + lq) ^ (row & 7)) * 8)];
            }
#pragma unroll
            for (int n = 0; n < 2; ++n) {
                const int row = wn * 32 + n * 16 + l15;
                wf[n] = *(const short8*)
                    &wb[row * 64 + (((kk * 4 + lq) ^ (row & 7)) * 8)];
            }
#pragma unroll
            for (int m = 0; m < 2; ++m)
#pragma unroll
                for (int n = 0; n < 2; ++n)
                    acc[m][n] = __builtin_amdgcn_mfma_f32_16x16x32_bf16(
                        af[m], wf[n], acc[m][n], 0, 0, 0);
        }
    };

    // ---- pipelined k-loop (NK % 4 == 0 for all instances) ----
    STAGE(0, 0); STAGE(1, 1); STAGE(2, 2);
#pragma unroll 1
    for (int p0 = 0; p0 < NK; p0 += 4) {
#pragma unroll
        for (int j = 0; j < 4; ++j) {
            const int p = p0 + j;
            // wait: stage p complete. in-flight stages = p..min(p+2,NK-1).
            if (p + 2 < NK)      asm volatile("s_waitcnt vmcnt(8)" ::: "memory");
            else if (p + 1 < NK) asm volatile("s_waitcnt vmcnt(4)" ::: "memory");
            else                 asm volatile("s_waitcnt vmcnt(0)" ::: "memory");
            __builtin_amdgcn_s_barrier();
            if (p + 3 < NK) STAGE(p + 3, (j + 3) & 3);
            COMPUTE(j);
        }
    }

    // --- epilogue ----------------------------------------------------------
    if constexpr (GATES) {
        float* zs = (float*)&lds[0];          // 64*65*4 = 16.6 KB <= 64 KB
        __syncthreads();
#pragma unroll
        for (int m = 0; m < 2; ++m)
#pragma unroll
            for (int n = 0; n < 2; ++n)
#pragma unroll
                for (int r = 0; r < 4; ++r)
                    zs[(wm * 32 + m * 16 + lq * 4 + r) * 65 +
                       wn * 32 + n * 16 + l15] = acc[m][n][r];
        __syncthreads();

        const int row = tid & 63;
        const int jl0 = (tid >> 6) * 4;
        const int grow = m0 + row;
        const int jg = n_tile * 16 + jl0;
        const f32x4 bi4 = *(const f32x4*)&bias[n0 + jl0];
        const f32x4 bf4 = *(const f32x4*)&bias[n0 + 16 + jl0];
        const f32x4 bg4 = *(const f32x4*)&bias[n0 + 32 + jl0];
        const f32x4 bo4 = *(const f32x4*)&bias[n0 + 48 + jl0];
        f32x4 cv = *(f32x4*)&c[(size_t)grow * H_SZ + jg];
        ushort hh[4], hl[4];
#pragma unroll
        for (int jj = 0; jj < 4; ++jj) {
            const float zi = zs[row * 65 + jl0 + jj] + bi4[jj];
            const float zf = zs[row * 65 + 16 + jl0 + jj] + bf4[jj];
            const float zg = zs[row * 65 + 32 + jl0 + jj] + bg4[jj];
            const float zo = zs[row * 65 + 48 + jl0 + jj] + bo4[jj];
            const float ig = 1.f / (1.f + expf(-zi));
            const float fg = 1.f / (1.f + expf(-zf));
            const float gg = tanhf(zg);
            const float og = 1.f / (1.f + expf(-zo));
            const float cn = fg * cv[jj] + ig * gg;
            cv[jj] = cn;
            const float hv = og * tanhf(cn);
            hh[jj] = f2bf(hv);
            hl[jj] = f2bf(hv - bf2f(hh[jj]));
        }
        *(f32x4*)&c[(size_t)grow * H_SZ + jg] = cv;
        ushort* hd = hdest + (size_t)grow * ldh + jg;
        uint hv2[2], lv2[2];
        hv2[0] = (uint)hh[0] | ((uint)hh[1] << 16);
        hv2[1] = (uint)hh[2] | ((uint)hh[3] << 16);
        lv2[0] = (uint)hl[0] | ((uint)hl[1] << 16);
        lv2[1] = (uint)hl[2] | ((uint)hl[3] << 16);
        *(uint*)&hd[0] = hv2[0];
        *(uint*)&hd[2] = hv2[1];
        *(uint*)&hd[1024] = lv2[0];
        *(uint*)&hd[1026] = lv2[1];            // h_lo always hi_base + 1024

        if (xdest) {                            // fused x_{t+1} conversion
            const int idx = flat * 256 + tid;   // exactly B*I = 131072
            const int b = idx >> 8, i = idx & 255;
            const float v = xsrc[(size_t)b * (T_SZ * I_SZ) + i];
            const ushort hi = f2bf(v), lo = f2bf(v - bf2f(hi));
            xdest[(size_t)b * APE + i] = hi;
            xdest[(size_t)b * APE + 256 + i] = lo;
        }
    } else {
#pragma unroll
        for (int m = 0; m < 2; ++m)
#pragma unroll
            for (int n = 0; n < 2; ++n) {
                const int col = n0 + wn * 32 + n * 16 + l15;
                const float bv = bias[col];
#pragma unroll
                for (int r = 0; r < 4; ++r) {
                    const int row = m0 + wm * 32 + m * 16 + lq * 4 + r;
                    out[(size_t)row * ldo + col] = acc[m][n][r] + bv;
                }
            }
    }
}

// ---------------------------------------------------------------------------
// Row argmax (first-occurrence) + embedding gather into next dec A's xc.
// ---------------------------------------------------------------------------
__global__ __launch_bounds__(256) void argmax_embed(
    const float* __restrict__ logits, int ldl,
    const float* __restrict__ embed_W,
    ushort* __restrict__ xdest)
{
    const int b = blockIdx.x;
    const float* row = logits + (size_t)b * ldl;
    const int tid = threadIdx.x;
    float best = -INFINITY;
    int bi = V_SZ;
#pragma unroll
    for (int v = tid; v < V_SZ; v += 256) {
        const float x = row[v];
        if (x > best) { best = x; bi = v; }
    }
    __shared__ float sv[256];
    __shared__ int si[256];
    sv[tid] = best; si[tid] = bi;
    __syncthreads();
    for (int s = 128; s > 0; s >>= 1) {
        if (tid < s) {
            const float ov = sv[tid + s]; const int oi = si[tid + s];
            if (ov > sv[tid] || (ov == sv[tid] && oi < si[tid])) { sv[tid] = ov; si[tid] = oi; }
        }
        __syncthreads();
    }
    if (tid < E_SZ) {
        const int yb = si[0];
        const float v = embed_W[(size_t)yb * E_SZ + tid];
        const ushort hi = f2bf(v), lo = f2bf(v - bf2f(hi));
        ushort* xd = xdest + (size_t)b * APD;
        xd[tid] = hi;
        xd[8 + tid] = hi;
        xd[16 + tid] = lo;
    }
}

// ---------------------------------------------------------------------------
// Weight packing (gate-permuted rows n' = jhi*64 + g*16 + jlo).
// ---------------------------------------------------------------------------
__global__ void pack_enc(const float* __restrict__ Wih, const float* __restrict__ Whh,
                         const float* __restrict__ b, ushort* __restrict__ Wp,
                         float* __restrict__ bp)
{
    const int k = blockIdx.x * 256 + threadIdx.x;   // < 3840
    const int np = blockIdx.y;                      // < 4096
    const int orig = ((np >> 4) & 3) * H_SZ + (np >> 6) * 16 + (np & 15);
    float v; bool lo = false;
    if (k < 256)        v = Wih[(size_t)orig * I_SZ + k];
    else if (k < 512) { v = Wih[(size_t)orig * I_SZ + k - 256]; lo = true; }
    else if (k < 768)   v = Wih[(size_t)orig * I_SZ + k - 512];
    else if (k < 1792)  v = Whh[(size_t)orig * H_SZ + k - 768];
    else if (k < 2816) { v = Whh[(size_t)orig * H_SZ + k - 1792]; lo = true; }
    else                v = Whh[(size_t)orig * H_SZ + k - 2816];
    const ushort hi = f2bf(v);
    Wp[(size_t)np * KVE + k] = lo ? f2bf(v - bf2f(hi)) : hi;
    if (k == 0) bp[np] = b[orig];
}

__global__ void pack_dec(const float* __restrict__ Wih, const float* __restrict__ Whh,
                         const float* __restrict__ b, ushort* __restrict__ Wp,
                         float* __restrict__ bp)
{
    const int k = blockIdx.x * 256 + threadIdx.x;   // < 3328 (13*256 exact)
    const int np = blockIdx.y;
    const int orig = ((np >> 4) & 3) * H_SZ + (np >> 6) * 16 + (np & 15);
    float v = 0.f; bool lo = false; bool zero = false;
    if (k < 8)            v = Wih[(size_t)orig * E_SZ + k];
    else if (k < 16)    { v = Wih[(size_t)orig * E_SZ + k - 8]; lo = true; }
    else if (k < 24)      v = Wih[(size_t)orig * E_SZ + k - 16];
    else if (k < 128)     zero = true;
    else if (k < 1152)    v = Whh[(size_t)orig * H_SZ + k - 128];
    else if (k < 2176)  { v = Whh[(size_t)orig * H_SZ + k - 1152]; lo = true; }
    else if (k < 3200)    v = Whh[(size_t)orig * H_SZ + k - 2176];
    else                  zero = true;
    ushort w = 0;
    if (!zero) { const ushort hi = f2bf(v); w = lo ? f2bf(v - bf2f(hi)) : hi; }
    Wp[(size_t)np * KVD + k] = w;
    if (k == 0) bp[np] = b[orig];
}

__global__ void pack_fc(const float* __restrict__ W, ushort* __restrict__ Wp)
{
    const int k = blockIdx.x * 256 + threadIdx.x;   // < 3072
    const int np = blockIdx.y;                      // < 1024 (no permute)
    float v; bool lo = false;
    if (k < 1024)       v = W[(size_t)np * H_SZ + k];
    else if (k < 2048) { v = W[(size_t)np * H_SZ + k - 1024]; lo = true; }
    else                v = W[(size_t)np * H_SZ + k - 2048];
    const ushort hi = f2bf(v);
    Wp[(size_t)np * KVF + k] = lo ? f2bf(v - bf2f(hi)) : hi;
}

// ---------------------------------------------------------------------------
// Init: zero c + A_enc0 h region; convert x(0); xc(0) from embed row 0;
// zero dec xc pads (both buffers).
// ---------------------------------------------------------------------------
__global__ void init_all(const float* __restrict__ x0,
                         const float* __restrict__ embed_W,
                         float* __restrict__ c,
                         ushort* __restrict__ Aenc0,
                         ushort* __restrict__ Adec0,
                         ushort* __restrict__ Adec1)
{
    const int idx = blockIdx.x * 256 + threadIdx.x;   // < 512*2048
    {
        const int b = idx >> 11, k = idx & 2047;
        Aenc0[(size_t)b * APE + 512 + k] = 0;
    }
    if (idx < B_SZ * H_SZ) c[idx] = 0.f;
    if (idx < B_SZ * I_SZ) {
        const int b = idx >> 8, i = idx & 255;
        const float v = x0[(size_t)b * (T_SZ * I_SZ) + i];
        const ushort hi = f2bf(v), lo = f2bf(v - bf2f(hi));
        Aenc0[(size_t)b * APE + i] = hi;
        Aenc0[(size_t)b * APE + 256 + i] = lo;
    }
    if (idx < B_SZ * 104) {
        const int b = idx / 104, col = 24 + idx % 104;
        Adec0[(size_t)b * APD + col] = 0;
        Adec1[(size_t)b * APD + col] = 0;
    }
    if (idx < B_SZ * 24) {
        const int b = idx / 24, col = idx % 24;
        float v;
        if (col < 8)       v = embed_W[col];
        else if (col < 16) v = embed_W[col - 8];
        else               v = embed_W[col - 16];
        const ushort hi = f2bf(v);
        Adec0[(size_t)b * APD + col] = (col < 16) ? hi : f2bf(v - bf2f(hi));
    }
}

extern "C" void kernel_launch(void* const* d_in, const int* in_sizes, int n_in,
                              void* d_out, int out_size, void* d_ws, size_t ws_size,
                              hipStream_t stream)
{
    const float* x_hist  = (const float*)d_in[0];
    const float* enc_Wih = (const float*)d_in[1];
    const float* enc_Whh = (const float*)d_in[2];
    const float* enc_b   = (const float*)d_in[3];
    const float* embed_W = (const float*)d_in[4];
    const float* dec_Wih = (const float*)d_in[5];
    const float* dec_Whh = (const float*)d_in[6];
    const float* dec_b   = (const float*)d_in[7];
    const float* fc_W    = (const float*)d_in[8];
    const float* fc_b    = (const float*)d_in[9];
    float* out = (float*)d_out;

    char* p = (char*)d_ws;
    auto alloc = [&](size_t bytes) {
        char* r = p;
        p += (bytes + 255) & ~(size_t)255;
        return r;
    };
    ushort* W_enc  = (ushort*)alloc((size_t)4096 * KVE * 2);   // 30 MB
    ushort* W_dec  = (ushort*)alloc((size_t)4096 * KVD * 2);   // 26 MB
    ushort* W_fc   = (ushort*)alloc((size_t)1024 * KVF * 2);   // 6 MB
    ushort* A_enc0 = (ushort*)alloc((size_t)B_SZ * APE * 2);   // 2.5 MB
    ushort* A_enc1 = (ushort*)alloc((size_t)B_SZ * APE * 2);
    ushort* A_dec0 = (ushort*)alloc((size_t)B_SZ * APD * 2);   // 2.13 MB
    ushort* A_dec1 = (ushort*)alloc((size_t)B_SZ * APD * 2);
    float*  cbuf   = (float*)alloc((size_t)B_SZ * H_SZ * 4);   // 2 MB
    float*  bpe    = (float*)alloc(4096 * 4);
    float*  bpd    = (float*)alloc(4096 * 4);

    const dim3 blk(256);
    hipLaunchKernelGGL(pack_enc, dim3(15, 4096), blk, 0, stream, enc_Wih, enc_Whh, enc_b, W_enc, bpe);
    hipLaunchKernelGGL(pack_dec, dim3(13, 4096), blk, 0, stream, dec_Wih, dec_Whh, dec_b, W_dec, bpd);
    hipLaunchKernelGGL(pack_fc,  dim3(12, 1024), blk, 0, stream, fc_W, W_fc);
    hipLaunchKernelGGL(init_all, dim3(4096), blk, 0, stream, x_hist, embed_W, cbuf, A_enc0, A_dec0, A_dec1);

    ushort* Ae[2] = {A_enc0, A_enc1};
    ushort* Ad[2] = {A_dec0, A_dec1};

    // Encoder: A-map offsets per k-tile(64): [0,4):0 [4,28):-256 [28,60):-1280
    for (int t = 0; t < T_SZ; ++t) {
        ushort* hdst; int ldh; const float* xs; ushort* xd;
        if (t < T_SZ - 1) {
            hdst = Ae[(t + 1) & 1] + 512; ldh = APE;
            xs = x_hist + (size_t)(t + 1) * I_SZ;
            xd = Ae[(t + 1) & 1];
        } else {
            hdst = Ad[0] + 128; ldh = APD;
            xs = nullptr; xd = nullptr;
        }
        hipLaunchKernelGGL((gemm_step<8, 60, 4, 28, 0, -256, -1280, true>),
                           dim3(512), blk, 0, stream,
                           Ae[t & 1], APE, W_enc, KVE, bpe, cbuf,
                           hdst, ldh, xs, xd, (float*)nullptr, 0);
    }

    // Decoder: dec map: [0,18):0 [18,50):-1024 [50,52):-3200 (zero-pad tiles)
    // fc map:  [0,16):+128 [16,48):-896
    for (int t = 0; t < FUT; ++t) {
        hipLaunchKernelGGL((gemm_step<8, 52, 18, 50, 0, -1024, -3200, true>),
                           dim3(512), blk, 0, stream,
                           Ad[t & 1], APD, W_dec, KVD, bpd, cbuf,
                           Ad[(t + 1) & 1] + 128, APD,
                           (const float*)nullptr, (ushort*)nullptr,
                           (float*)nullptr, 0);
        float* logits = out + (size_t)t * V_SZ;   // [B, FUT, V]
        hipLaunchKernelGGL((gemm_step<2, 48, 16, 48, 128, -896, -896, false>),
                           dim3(128), blk, 0, stream,
                           Ad[(t + 1) & 1], APD, W_fc, KVF, fc_b,
                           (float*)nullptr, (ushort*)nullptr, 0,
                           (const float*)nullptr, (ushort*)nullptr,
                           logits, FUT * V_SZ);
        hipLaunchKernelGGL(argmax_embed, dim3(512), blk, 0, stream,
                           logits, FUT * V_SZ, embed_W, Ad[(t + 1) & 1]);
    }
}